// Round 1
// baseline (676.090 us; speedup 1.0000x reference)
//
#include <hip/hip_runtime.h>
#include <math.h>
#include <stdint.h>

typedef unsigned long long u64;
typedef unsigned int u32;

#define NCLS 80
#define NA   8400
#define NB   16
#define PRE_K 1000

// ---------------- ws layout (bytes) ----------------
// f_keys : u64   [NB][NA]      @ 0         (1,075,200)
// boxes  : float4[NB][NA]      @ 1,075,200 (2,150,400)
// labels : int   [NB][NA]      @ 3,225,600 (  537,600)
// cand   : u64   [NB][1024]    @ 3,763,200 (  131,072)
// mask   : u64   [NB][1000][16]@ 3,894,272 (2,048,000)
// total ~5.95 MB

__device__ inline u64 shfl64(u64 v, int src) {
    unsigned lo = (unsigned)__shfl((int)(u32)v, src, 64);
    unsigned hi = (unsigned)__shfl((int)(u32)(v >> 32), src, 64);
    return ((u64)hi << 32) | (u64)lo;
}

// ------------------------------------------------------------------
// Kernel 1: per-anchor max/argmax over 80 classes, sigmoid score,
// box decode, sort-key emit.
// ------------------------------------------------------------------
__global__ __launch_bounds__(256) void k_decode(
    const float* __restrict__ cls0, const float* __restrict__ cls1,
    const float* __restrict__ cls2, const float* __restrict__ box0,
    const float* __restrict__ box1, const float* __restrict__ box2,
    u64* __restrict__ f_keys, float4* __restrict__ boxes,
    int* __restrict__ labels)
{
    int a = blockIdx.x * blockDim.x + threadIdx.x;
    int b = blockIdx.y;
    if (a >= NA) return;

    const float* clsp; const float* boxp;
    int Wd, s, hw, HW;
    if (a < 6400)      { clsp = cls0; boxp = box0; Wd = 80; s = 8;  hw = a;        HW = 6400; }
    else if (a < 8000) { clsp = cls1; boxp = box1; Wd = 40; s = 16; hw = a - 6400; HW = 1600; }
    else               { clsp = cls2; boxp = box2; Wd = 20; s = 32; hw = a - 8000; HW = 400;  }

    const float* cp = clsp + (size_t)b * NCLS * HW + hw;
    float m = cp[0];
    int lab = 0;
#pragma unroll 8
    for (int c = 1; c < NCLS; ++c) {
        float v = cp[(size_t)c * HW];
        if (v > m) { m = v; lab = c; }   // strict > keeps first index on ties
    }
    // sigmoid of the max logit, double-accurate then rounded to f32
    double e = exp(-(double)m);
    float sc = (float)(1.0 / (1.0 + e));
    float sz = (sc > 0.25f) ? sc : 0.0f;  // zeroed-where-invalid score (top_k input)
    f_keys[(size_t)b * NA + a] = ((u64)__float_as_uint(sz) << 32) | (u64)(~(u32)a);

    const float* bp = boxp + (size_t)b * 4 * HW + hw;
    float fs = (float)s;
    float d0 = bp[0] * fs, d1 = bp[HW] * fs, d2 = bp[2 * HW] * fs, d3 = bp[3 * HW] * fs;
    float px = (float)((hw % Wd) * s);
    float py = (float)((hw / Wd) * s);
    boxes[(size_t)b * NA + a] = make_float4(px - d0, py - d1, px + d2, py + d3);
    labels[(size_t)b * NA + a] = lab;
}

// ------------------------------------------------------------------
// Kernel 2: per-batch exact descending sort (score, then index asc)
// bitonic 8192 (anchors 0..8191) + bitonic 256 (anchors 8192..8399,
// padded with key=0) + merge-by-rank -> top-1000 keys to `cand`.
// ------------------------------------------------------------------
__global__ __launch_bounds__(1024) void k_sort(
    const u64* __restrict__ f_keys, u64* __restrict__ cand)
{
    __shared__ u64 sh[8192];                 // 64 KB
    int b = blockIdx.x, tid = threadIdx.x;
    const u64* fk = f_keys + (size_t)b * NA;

    for (int i = tid; i < 8192; i += 1024) sh[i] = fk[i];
    __syncthreads();

    // descending bitonic over 8192
    for (int k = 2; k <= 8192; k <<= 1) {
        for (int j = k >> 1; j > 0; j >>= 1) {
            for (int t = tid; t < 4096; t += 1024) {
                int i = ((t & ~(j - 1)) << 1) | (t & (j - 1));
                int l = i | j;
                u64 x = sh[i], y = sh[l];
                bool sw = ((i & k) == 0) ? (x < y) : (x > y);
                if (sw) { sh[i] = y; sh[l] = x; }
            }
            __syncthreads();
        }
    }

    // tail (208 anchors) into dead region sh[7936..8191], pad key=0
    if (tid < 256) sh[7936 + tid] = (tid < 208) ? fk[8192 + tid] : 0ull;
    __syncthreads();
    for (int k = 2; k <= 256; k <<= 1) {
        for (int j = k >> 1; j > 0; j >>= 1) {
            for (int t = tid; t < 128; t += 1024) {
                int i = ((t & ~(j - 1)) << 1) | (t & (j - 1));
                int l = i | j;
                u64 x = sh[7936 + i], y = sh[7936 + l];
                bool sw = ((i & k) == 0) ? (x < y) : (x > y);
                if (sw) { sh[7936 + i] = y; sh[7936 + l] = x; }
            }
            __syncthreads();
        }
    }

    u64* cb = cand + (size_t)b * 1024;
    // merge: rank of A[i] = i + |B > A[i]|   (keys are all distinct)
    if (tid < 1000) {
        u64 x = sh[tid];
        int lo = 0, hi = 256;
        while (lo < hi) { int mid = (lo + hi) >> 1; if (sh[7936 + mid] > x) lo = mid + 1; else hi = mid; }
        int r = tid + lo;
        if (r < PRE_K) cb[r] = x;
    }
    // rank of B[j] = j + |A > B[j]| (search top-1024 of A suffices)
    if (tid < 256) {
        u64 x = sh[7936 + tid];
        int lo = 0, hi = 1024;
        while (lo < hi) { int mid = (lo + hi) >> 1; if (sh[mid] > x) lo = mid + 1; else hi = mid; }
        int r = tid + lo;
        if (r < PRE_K) cb[r] = x;
    }
}

// ------------------------------------------------------------------
// Kernel 3: IoU(thr) bitmask matrix on class-offset boxes.
// mask[b][i][w] bit jj  <=>  iou(cand_i, cand_{64w+jj}) > 0.65
// grid (4 row-chunks, 16 batches), block 1024.
// ------------------------------------------------------------------
__global__ __launch_bounds__(1024) void k_iou(
    const u64* __restrict__ cand, const float4* __restrict__ boxes,
    const int* __restrict__ labels, u64* __restrict__ mask)
{
    __shared__ float sx1[1000], sy1[1000], sx2[1000], sy2[1000], sar[1000];
    int b = blockIdx.y, chunk = blockIdx.x, tid = threadIdx.x;
    const u64* cb = cand + (size_t)b * 1024;

    for (int i = tid; i < PRE_K; i += 1024) {
        u64 key = cb[i];
        u32 a = ~(u32)key;
        float4 bx = boxes[(size_t)b * NA + a];
        float off = (float)labels[(size_t)b * NA + a] * 8192.0f;  // exact mult
        float x1 = bx.x + off, y1 = bx.y + off, x2 = bx.z + off, y2 = bx.w + off;
        sx1[i] = x1; sy1[i] = y1; sx2[i] = x2; sy2[i] = y2;
        float w = fmaxf(__fsub_rn(x2, x1), 0.0f);
        float h = fmaxf(__fsub_rn(y2, y1), 0.0f);
        sar[i] = __fmul_rn(w, h);
    }
    __syncthreads();

    for (int w0 = tid; w0 < 4000; w0 += 1024) {
        int il = w0 % 250, jw = w0 / 250;
        int i = chunk * 250 + il;
        float ax1 = sx1[i], ay1 = sy1[i], ax2 = sx2[i], ay2 = sy2[i], aar = sar[i];
        int jmax = min(64, PRE_K - jw * 64);
        u64 bits = 0;
        for (int jj = 0; jj < jmax; ++jj) {
            int j = jw * 64 + jj;                 // uniform across most of a wave -> LDS broadcast
            float lx = fmaxf(ax1, sx1[j]), ly = fmaxf(ay1, sy1[j]);
            float rx = fminf(ax2, sx2[j]), ry = fminf(ay2, sy2[j]);
            float ww = fmaxf(__fsub_rn(rx, lx), 0.0f);
            float hh = fmaxf(__fsub_rn(ry, ly), 0.0f);
            float inter = __fmul_rn(ww, hh);
            float uni = __fsub_rn(__fadd_rn(aar, sar[j]), inter);  // (ai+aj)-inter, no FMA
            float den = fmaxf(uni, 1e-6f);
            float iou = inter / den;
            if (iou > 0.65f) bits |= (1ull << jj);
        }
        mask[((size_t)b * PRE_K + i) * 16 + jw] = bits;
    }
}

// ------------------------------------------------------------------
// Kernel 4: serial greedy-NMS scan (one wave per batch) + output.
// suppressed state: lane L (0..15) holds bits for candidates 64L..64L+63.
// `cur` mirrors the current 64-candidate chunk in every lane so the
// per-step critical path is pure ALU; rows + scalar words prefetched D=4.
// ------------------------------------------------------------------
__global__ __launch_bounds__(64) void k_nms(
    const u64* __restrict__ cand, const float4* __restrict__ boxes,
    const int* __restrict__ labels, const u64* __restrict__ mask,
    float* __restrict__ out)
{
    int b = blockIdx.x, lane = threadIdx.x;
    const u64* cb = cand + (size_t)b * 1024;
    const u64* mb = mask + (size_t)b * PRE_K * 16;

    // suppressed init = ~valid  (pads i>=1000 suppressed)
    u64 sup = 0;
    for (int r = 0; r < 16; ++r) {
        int i = r * 64 + lane;
        u64 key = (i < PRE_K) ? cb[i] : 0ull;
        float sc = __uint_as_float((u32)(key >> 32));
        bool val = (i < PRE_K) && (sc > 0.25f);
        u64 mball = __ballot(val);
        if (lane == r) sup = ~mball;
    }

    u64 pr[4], ps[4];
#pragma unroll
    for (int d = 0; d < 4; ++d) {
        pr[d] = (lane < 16) ? mb[(size_t)d * 16 + lane] : 0ull;
        ps[d] = mb[(size_t)d * 16 + 0];     // (d>>6)==0 for d<4
    }
    u64 cur = shfl64(sup, 0);
    u64 keepm = 0;

    for (int i = 0; i < PRE_K; ++i) {
        if (i && ((i & 63) == 0)) cur = shfl64(sup, i >> 6);  // chunk refresh (uniform)
        int slot = i & 3;
        u64 row = pr[slot], sw = ps[slot];
        int ip = i + 4;
        pr[slot] = (ip < PRE_K && lane < 16) ? mb[(size_t)ip * 16 + lane] : 0ull;
        ps[slot] = (ip < PRE_K) ? mb[(size_t)ip * 16 + (ip >> 6)] : 0ull;
        u64 bit = 1ull << (i & 63);
        bool keep_i = ((cur & bit) == 0);   // uniform across wave
        if (keep_i) {
            sup |= row;
            cur |= sw;
            cur &= ~bit;                     // suppressed[i] = !keep_i = 0
            if (lane == (i >> 6)) { sup &= ~bit; keepm |= bit; }
        }
    }

    // prefix of kept counts across the 16 chunks
    int cnt = __popcll(keepm);
    int pre = 0, K = 0;
    for (int w = 0; w < 16; ++w) {
        int c = __shfl(cnt, w, 64);
        if (w < lane) pre += c;
        K += c;
    }

    if (lane < 16) {
        for (int t = 0; t < 64; ++t) {
            int i = lane * 64 + t;
            if (i >= PRE_K) break;
            u64 bit = 1ull << t;
            int kb = __popcll(keepm & (bit - 1));
            int row; float fsc;
            u64 key = cb[i];
            if (keepm & bit) { row = pre + kb; fsc = __uint_as_float((u32)(key >> 32)); }
            else             { row = K + (i - (pre + kb)); fsc = 0.0f; }  // zero-score backfill, index order
            if (row < 100) {
                u32 a = ~(u32)key;
                float4 bx = boxes[(size_t)b * NA + a];
                int lab = labels[(size_t)b * NA + a];
                float* dr = out + (size_t)(b * 100 + row) * 5;
                dr[0] = bx.x; dr[1] = bx.y; dr[2] = bx.z; dr[3] = bx.w; dr[4] = fsc;
                out[(size_t)NB * 100 * 5 + b * 100 + row] = (float)lab;
            }
        }
    }
}

extern "C" void kernel_launch(void* const* d_in, const int* in_sizes, int n_in,
                              void* d_out, int out_size, void* d_ws, size_t ws_size,
                              hipStream_t stream) {
    const float* cls0 = (const float*)d_in[0];
    const float* cls1 = (const float*)d_in[1];
    const float* cls2 = (const float*)d_in[2];
    const float* box0 = (const float*)d_in[3];
    const float* box1 = (const float*)d_in[4];
    const float* box2 = (const float*)d_in[5];
    float* out = (float*)d_out;

    char* w = (char*)d_ws;
    u64*    f_keys = (u64*)(w);
    float4* boxes  = (float4*)(w + 1075200);
    int*    labels = (int*)(w + 3225600);
    u64*    cand   = (u64*)(w + 3763200);
    u64*    mask   = (u64*)(w + 3894272);

    k_decode<<<dim3(33, NB), 256, 0, stream>>>(cls0, cls1, cls2, box0, box1, box2,
                                               f_keys, boxes, labels);
    k_sort<<<NB, 1024, 0, stream>>>(f_keys, cand);
    k_iou<<<dim3(4, NB), 1024, 0, stream>>>(cand, boxes, labels, mask);
    k_nms<<<NB, 64, 0, stream>>>(cand, boxes, labels, mask, out);
}

// Round 2
// 361.105 us; speedup vs baseline: 1.8723x; 1.8723x over previous
//
#include <hip/hip_runtime.h>
#include <math.h>
#include <stdint.h>

typedef unsigned long long u64;
typedef unsigned int u32;

#define NCLS 80
#define NA   8400
#define NB   16
#define PRE_K 1000

// ---------------- ws layout (bytes) ----------------
// f_keys : u64   [NB][NA]      @ 0         (1,075,200)
// boxes  : float4[NB][NA]      @ 1,075,200 (2,150,400)
// labels : int   [NB][NA]      @ 3,225,600 (  537,600)
// cand   : u64   [NB][1024]    @ 3,763,200 (  131,072)
// mask   : u64   [NB][1000][16]@ 3,894,272 (2,048,000)
// total ~5.95 MB

__device__ inline u64 shfl64(u64 v, int src) {
    unsigned lo = (unsigned)__shfl((int)(u32)v, src, 64);
    unsigned hi = (unsigned)__shfl((int)(u32)(v >> 32), src, 64);
    return ((u64)hi << 32) | (u64)lo;
}

// ------------------------------------------------------------------
// Kernel 1: per-anchor max/argmax over 80 classes, sigmoid score,
// box decode, sort-key emit.
// ------------------------------------------------------------------
__global__ __launch_bounds__(256) void k_decode(
    const float* __restrict__ cls0, const float* __restrict__ cls1,
    const float* __restrict__ cls2, const float* __restrict__ box0,
    const float* __restrict__ box1, const float* __restrict__ box2,
    u64* __restrict__ f_keys, float4* __restrict__ boxes,
    int* __restrict__ labels)
{
    int a = blockIdx.x * blockDim.x + threadIdx.x;
    int b = blockIdx.y;
    if (a >= NA) return;

    const float* clsp; const float* boxp;
    int Wd, s, hw, HW;
    if (a < 6400)      { clsp = cls0; boxp = box0; Wd = 80; s = 8;  hw = a;        HW = 6400; }
    else if (a < 8000) { clsp = cls1; boxp = box1; Wd = 40; s = 16; hw = a - 6400; HW = 1600; }
    else               { clsp = cls2; boxp = box2; Wd = 20; s = 32; hw = a - 8000; HW = 400;  }

    const float* cp = clsp + (size_t)b * NCLS * HW + hw;
    float m = cp[0];
    int lab = 0;
#pragma unroll 8
    for (int c = 1; c < NCLS; ++c) {
        float v = cp[(size_t)c * HW];
        if (v > m) { m = v; lab = c; }   // strict > keeps first index on ties
    }
    // sigmoid of the max logit, double-accurate then rounded to f32
    double e = exp(-(double)m);
    float sc = (float)(1.0 / (1.0 + e));
    float sz = (sc > 0.25f) ? sc : 0.0f;  // zeroed-where-invalid score (top_k input)
    f_keys[(size_t)b * NA + a] = ((u64)__float_as_uint(sz) << 32) | (u64)(~(u32)a);

    const float* bp = boxp + (size_t)b * 4 * HW + hw;
    float fs = (float)s;
    float d0 = bp[0] * fs, d1 = bp[HW] * fs, d2 = bp[2 * HW] * fs, d3 = bp[3 * HW] * fs;
    float px = (float)((hw % Wd) * s);
    float py = (float)((hw / Wd) * s);
    boxes[(size_t)b * NA + a] = make_float4(px - d0, py - d1, px + d2, py + d3);
    labels[(size_t)b * NA + a] = lab;
}

// ------------------------------------------------------------------
// Kernel 2: per-batch exact descending sort (score, then index asc)
// bitonic 8192 (anchors 0..8191) + bitonic 256 (anchors 8192..8399,
// padded with key=0) + merge-by-rank -> top-1000 keys to `cand`.
// ------------------------------------------------------------------
__global__ __launch_bounds__(1024) void k_sort(
    const u64* __restrict__ f_keys, u64* __restrict__ cand)
{
    __shared__ u64 sh[8192];                 // 64 KB
    int b = blockIdx.x, tid = threadIdx.x;
    const u64* fk = f_keys + (size_t)b * NA;

    for (int i = tid; i < 8192; i += 1024) sh[i] = fk[i];
    __syncthreads();

    // descending bitonic over 8192
    for (int k = 2; k <= 8192; k <<= 1) {
        for (int j = k >> 1; j > 0; j >>= 1) {
            for (int t = tid; t < 4096; t += 1024) {
                int i = ((t & ~(j - 1)) << 1) | (t & (j - 1));
                int l = i | j;
                u64 x = sh[i], y = sh[l];
                bool sw = ((i & k) == 0) ? (x < y) : (x > y);
                if (sw) { sh[i] = y; sh[l] = x; }
            }
            __syncthreads();
        }
    }

    // tail (208 anchors) into dead region sh[7936..8191], pad key=0
    if (tid < 256) sh[7936 + tid] = (tid < 208) ? fk[8192 + tid] : 0ull;
    __syncthreads();
    for (int k = 2; k <= 256; k <<= 1) {
        for (int j = k >> 1; j > 0; j >>= 1) {
            for (int t = tid; t < 128; t += 1024) {
                int i = ((t & ~(j - 1)) << 1) | (t & (j - 1));
                int l = i | j;
                u64 x = sh[7936 + i], y = sh[7936 + l];
                bool sw = ((i & k) == 0) ? (x < y) : (x > y);
                if (sw) { sh[7936 + i] = y; sh[7936 + l] = x; }
            }
            __syncthreads();
        }
    }

    u64* cb = cand + (size_t)b * 1024;
    // merge: rank of A[i] = i + |B > A[i]|   (keys are all distinct)
    if (tid < 1000) {
        u64 x = sh[tid];
        int lo = 0, hi = 256;
        while (lo < hi) { int mid = (lo + hi) >> 1; if (sh[7936 + mid] > x) lo = mid + 1; else hi = mid; }
        int r = tid + lo;
        if (r < PRE_K) cb[r] = x;
    }
    // rank of B[j] = j + |A > B[j]| (search top-1024 of A suffices)
    if (tid < 256) {
        u64 x = sh[7936 + tid];
        int lo = 0, hi = 1024;
        while (lo < hi) { int mid = (lo + hi) >> 1; if (sh[mid] > x) lo = mid + 1; else hi = mid; }
        int r = tid + lo;
        if (r < PRE_K) cb[r] = x;
    }
}

// ------------------------------------------------------------------
// Kernel 3: IoU(thr) bitmask matrix on class-offset boxes.
// mask[b][i][w] bit jj  <=>  iou(cand_i, cand_{64w+jj}) > 0.65
// grid (4 row-chunks, 16 batches), block 1024.
// ------------------------------------------------------------------
__global__ __launch_bounds__(1024) void k_iou(
    const u64* __restrict__ cand, const float4* __restrict__ boxes,
    const int* __restrict__ labels, u64* __restrict__ mask)
{
    __shared__ float sx1[1000], sy1[1000], sx2[1000], sy2[1000], sar[1000];
    int b = blockIdx.y, chunk = blockIdx.x, tid = threadIdx.x;
    const u64* cb = cand + (size_t)b * 1024;

    for (int i = tid; i < PRE_K; i += 1024) {
        u64 key = cb[i];
        u32 a = ~(u32)key;
        float4 bx = boxes[(size_t)b * NA + a];
        float off = (float)labels[(size_t)b * NA + a] * 8192.0f;  // exact mult
        float x1 = bx.x + off, y1 = bx.y + off, x2 = bx.z + off, y2 = bx.w + off;
        sx1[i] = x1; sy1[i] = y1; sx2[i] = x2; sy2[i] = y2;
        float w = fmaxf(__fsub_rn(x2, x1), 0.0f);
        float h = fmaxf(__fsub_rn(y2, y1), 0.0f);
        sar[i] = __fmul_rn(w, h);
    }
    __syncthreads();

    for (int w0 = tid; w0 < 4000; w0 += 1024) {
        int il = w0 % 250, jw = w0 / 250;
        int i = chunk * 250 + il;
        float ax1 = sx1[i], ay1 = sy1[i], ax2 = sx2[i], ay2 = sy2[i], aar = sar[i];
        int jmax = min(64, PRE_K - jw * 64);
        u64 bits = 0;
        for (int jj = 0; jj < jmax; ++jj) {
            int j = jw * 64 + jj;                 // uniform across most of a wave -> LDS broadcast
            float lx = fmaxf(ax1, sx1[j]), ly = fmaxf(ay1, sy1[j]);
            float rx = fminf(ax2, sx2[j]), ry = fminf(ay2, sy2[j]);
            float ww = fmaxf(__fsub_rn(rx, lx), 0.0f);
            float hh = fmaxf(__fsub_rn(ry, ly), 0.0f);
            float inter = __fmul_rn(ww, hh);
            float uni = __fsub_rn(__fadd_rn(aar, sar[j]), inter);  // (ai+aj)-inter, no FMA
            float den = fmaxf(uni, 1e-6f);
            float iou = inter / den;
            if (iou > 0.65f) bits |= (1ull << jj);
        }
        mask[((size_t)b * PRE_K + i) * 16 + jw] = bits;
    }
}

// ------------------------------------------------------------------
// Kernel 4: serial greedy-NMS scan (one wave per batch) + output.
// suppressed state: lane L (0..15) holds bits for candidates 64L..64L+63.
// `cur` mirrors the current 64-candidate chunk in every lane so the
// per-step critical path is pure ALU.
// Prefetch depth 8, FULLY UNROLLED inner 8 so the pipeline buffers are
// compile-time indexed -> VGPRs, not scratch. (R1: pr[slot] with runtime
// slot demoted buffers to scratch -> 1085 cyc/step.)
// ------------------------------------------------------------------
__global__ __launch_bounds__(64) void k_nms(
    const u64* __restrict__ cand, const float4* __restrict__ boxes,
    const int* __restrict__ labels, const u64* __restrict__ mask,
    float* __restrict__ out)
{
    int b = blockIdx.x, lane = threadIdx.x;
    const u64* cb = cand + (size_t)b * 1024;
    const u64* mb = mask + (size_t)b * PRE_K * 16;
    int lw = lane & 15;   // row word this lane mirrors (replicated x4)

    // suppressed init = ~valid  (pads i>=1000 suppressed)
    u64 sup = 0;
    for (int r = 0; r < 16; ++r) {
        int i = r * 64 + lane;
        u64 key = (i < PRE_K) ? cb[i] : 0ull;
        float sc = __uint_as_float((u32)(key >> 32));
        bool val = (i < PRE_K) && (sc > 0.25f);
        u64 mball = __ballot(val);
        if (lane == r) sup = ~mball;
    }

    u64 pr[8], ps[8];
#pragma unroll
    for (int d = 0; d < 8; ++d) {
        pr[d] = mb[(size_t)d * 16 + lw];
        ps[d] = mb[(size_t)d * 16 + 0];     // (d>>6)==0 for d<8
    }
    u64 cur = shfl64(sup, 0);
    u64 keepm = 0;

    for (int i0 = 0; i0 < PRE_K; i0 += 8) {
        if (i0 && ((i0 & 63) == 0)) cur = shfl64(sup, i0 >> 6);  // chunk refresh
#pragma unroll
        for (int u = 0; u < 8; ++u) {
            int i = i0 + u;
            u64 row = pr[u], sw = ps[u];
            int ip = i + 8;
            int ipc = (ip < PRE_K) ? ip : (PRE_K - 1);   // clamp, no predication
            pr[u] = mb[(size_t)ipc * 16 + lw];
            ps[u] = mb[(size_t)ipc * 16 + (ipc >> 6)];
            u64 bit = 1ull << (i & 63);
            u64 m = ((cur & bit) == 0) ? ~0ull : 0ull;   // keep_i mask, branchless
            u64 lbit = (lane == (i >> 6)) ? bit : 0ull;
            sup = (sup | (row & m)) & ~(lbit & m);
            cur = (cur | (sw & m)) & ~(bit & m);
            keepm |= lbit & m;
        }
    }

    // prefix of kept counts across the 16 chunks
    int cnt = __popcll(keepm);
    int pre = 0, K = 0;
    for (int w = 0; w < 16; ++w) {
        int c = __shfl(cnt, w, 64);
        if (w < lane) pre += c;
        K += c;
    }

    if (lane < 16) {
        for (int t = 0; t < 64; ++t) {
            int i = lane * 64 + t;
            if (i >= PRE_K) break;
            u64 bit = 1ull << t;
            int kb = __popcll(keepm & (bit - 1));
            int row; float fsc;
            u64 key = cb[i];
            if (keepm & bit) { row = pre + kb; fsc = __uint_as_float((u32)(key >> 32)); }
            else             { row = K + (i - (pre + kb)); fsc = 0.0f; }  // zero-score backfill, index order
            if (row < 100) {
                u32 a = ~(u32)key;
                float4 bx = boxes[(size_t)b * NA + a];
                int lab = labels[(size_t)b * NA + a];
                float* dr = out + (size_t)(b * 100 + row) * 5;
                dr[0] = bx.x; dr[1] = bx.y; dr[2] = bx.z; dr[3] = bx.w; dr[4] = fsc;
                out[(size_t)NB * 100 * 5 + b * 100 + row] = (float)lab;
            }
        }
    }
}

extern "C" void kernel_launch(void* const* d_in, const int* in_sizes, int n_in,
                              void* d_out, int out_size, void* d_ws, size_t ws_size,
                              hipStream_t stream) {
    const float* cls0 = (const float*)d_in[0];
    const float* cls1 = (const float*)d_in[1];
    const float* cls2 = (const float*)d_in[2];
    const float* box0 = (const float*)d_in[3];
    const float* box1 = (const float*)d_in[4];
    const float* box2 = (const float*)d_in[5];
    float* out = (float*)d_out;

    char* w = (char*)d_ws;
    u64*    f_keys = (u64*)(w);
    float4* boxes  = (float4*)(w + 1075200);
    int*    labels = (int*)(w + 3225600);
    u64*    cand   = (u64*)(w + 3763200);
    u64*    mask   = (u64*)(w + 3894272);

    k_decode<<<dim3(33, NB), 256, 0, stream>>>(cls0, cls1, cls2, box0, box1, box2,
                                               f_keys, boxes, labels);
    k_sort<<<NB, 1024, 0, stream>>>(f_keys, cand);
    k_iou<<<dim3(4, NB), 1024, 0, stream>>>(cand, boxes, labels, mask);
    k_nms<<<NB, 64, 0, stream>>>(cand, boxes, labels, mask, out);
}

// Round 3
// 309.915 us; speedup vs baseline: 2.1815x; 1.1652x over previous
//
#include <hip/hip_runtime.h>
#include <math.h>
#include <stdint.h>

typedef unsigned long long u64;
typedef unsigned int u32;

#define NCLS 80
#define NA   8400
#define NB   16
#define PRE_K 1000

// ---------------- ws layout (bytes) ----------------
// f_keys : u64   [NB][NA]      @ 0         (1,075,200)
// boxes  : float4[NB][NA]      @ 1,075,200 (2,150,400)
// labels : int   [NB][NA]      @ 3,225,600 (  537,600)
// cand   : u64   [NB][1024]    @ 3,763,200 (  131,072)
// mask   : u64   [NB][1000][16]@ 3,894,272 (2,048,000)
// total ~5.95 MB

__device__ inline u64 shfl64(u64 v, int src) {
    unsigned lo = (unsigned)__shfl((int)(u32)v, src, 64);
    unsigned hi = (unsigned)__shfl((int)(u32)(v >> 32), src, 64);
    return ((u64)hi << 32) | (u64)lo;
}

// ------------------------------------------------------------------
// Kernel 1: per-anchor max/argmax over 80 classes, sigmoid score,
// box decode, sort-key emit.
// ------------------------------------------------------------------
__global__ __launch_bounds__(256) void k_decode(
    const float* __restrict__ cls0, const float* __restrict__ cls1,
    const float* __restrict__ cls2, const float* __restrict__ box0,
    const float* __restrict__ box1, const float* __restrict__ box2,
    u64* __restrict__ f_keys, float4* __restrict__ boxes,
    int* __restrict__ labels)
{
    int a = blockIdx.x * blockDim.x + threadIdx.x;
    int b = blockIdx.y;
    if (a >= NA) return;

    const float* clsp; const float* boxp;
    int Wd, s, hw, HW;
    if (a < 6400)      { clsp = cls0; boxp = box0; Wd = 80; s = 8;  hw = a;        HW = 6400; }
    else if (a < 8000) { clsp = cls1; boxp = box1; Wd = 40; s = 16; hw = a - 6400; HW = 1600; }
    else               { clsp = cls2; boxp = box2; Wd = 20; s = 32; hw = a - 8000; HW = 400;  }

    const float* cp = clsp + (size_t)b * NCLS * HW + hw;
    float m = cp[0];
    int lab = 0;
#pragma unroll 8
    for (int c = 1; c < NCLS; ++c) {
        float v = cp[(size_t)c * HW];
        if (v > m) { m = v; lab = c; }   // strict > keeps first index on ties
    }
    // sigmoid of the max logit, double-accurate then rounded to f32
    double e = exp(-(double)m);
    float sc = (float)(1.0 / (1.0 + e));
    float sz = (sc > 0.25f) ? sc : 0.0f;  // zeroed-where-invalid score (top_k input)
    f_keys[(size_t)b * NA + a] = ((u64)__float_as_uint(sz) << 32) | (u64)(~(u32)a);

    const float* bp = boxp + (size_t)b * 4 * HW + hw;
    float fs = (float)s;
    float d0 = bp[0] * fs, d1 = bp[HW] * fs, d2 = bp[2 * HW] * fs, d3 = bp[3 * HW] * fs;
    float px = (float)((hw % Wd) * s);
    float py = (float)((hw / Wd) * s);
    boxes[(size_t)b * NA + a] = make_float4(px - d0, py - d1, px + d2, py + d3);
    labels[(size_t)b * NA + a] = lab;
}

// ------------------------------------------------------------------
// Kernel 2: per-batch exact descending sort (score, then index asc)
// bitonic 8192 (anchors 0..8191) + bitonic 256 (anchors 8192..8399,
// padded with key=0) + merge-by-rank -> top-1000 keys to `cand`.
// ------------------------------------------------------------------
__global__ __launch_bounds__(1024) void k_sort(
    const u64* __restrict__ f_keys, u64* __restrict__ cand)
{
    __shared__ u64 sh[8192];                 // 64 KB
    int b = blockIdx.x, tid = threadIdx.x;
    const u64* fk = f_keys + (size_t)b * NA;

    for (int i = tid; i < 8192; i += 1024) sh[i] = fk[i];
    __syncthreads();

    // descending bitonic over 8192
    for (int k = 2; k <= 8192; k <<= 1) {
        for (int j = k >> 1; j > 0; j >>= 1) {
            for (int t = tid; t < 4096; t += 1024) {
                int i = ((t & ~(j - 1)) << 1) | (t & (j - 1));
                int l = i | j;
                u64 x = sh[i], y = sh[l];
                bool sw = ((i & k) == 0) ? (x < y) : (x > y);
                if (sw) { sh[i] = y; sh[l] = x; }
            }
            __syncthreads();
        }
    }

    // tail (208 anchors) into dead region sh[7936..8191], pad key=0
    if (tid < 256) sh[7936 + tid] = (tid < 208) ? fk[8192 + tid] : 0ull;
    __syncthreads();
    for (int k = 2; k <= 256; k <<= 1) {
        for (int j = k >> 1; j > 0; j >>= 1) {
            for (int t = tid; t < 128; t += 1024) {
                int i = ((t & ~(j - 1)) << 1) | (t & (j - 1));
                int l = i | j;
                u64 x = sh[7936 + i], y = sh[7936 + l];
                bool sw = ((i & k) == 0) ? (x < y) : (x > y);
                if (sw) { sh[7936 + i] = y; sh[7936 + l] = x; }
            }
            __syncthreads();
        }
    }

    u64* cb = cand + (size_t)b * 1024;
    // merge: rank of A[i] = i + |B > A[i]|   (keys are all distinct)
    if (tid < 1000) {
        u64 x = sh[tid];
        int lo = 0, hi = 256;
        while (lo < hi) { int mid = (lo + hi) >> 1; if (sh[7936 + mid] > x) lo = mid + 1; else hi = mid; }
        int r = tid + lo;
        if (r < PRE_K) cb[r] = x;
    }
    // rank of B[j] = j + |A > B[j]| (search top-1024 of A suffices)
    if (tid < 256) {
        u64 x = sh[7936 + tid];
        int lo = 0, hi = 1024;
        while (lo < hi) { int mid = (lo + hi) >> 1; if (sh[mid] > x) lo = mid + 1; else hi = mid; }
        int r = tid + lo;
        if (r < PRE_K) cb[r] = x;
    }
}

// ------------------------------------------------------------------
// Kernel 3: IoU(thr) bitmask matrix on class-offset boxes.
// mask[b][i][w] bit jj  <=>  iou(cand_i, cand_{64w+jj}) > 0.65
// grid (8 row-chunks, 16 batches), block 1024.
// ------------------------------------------------------------------
__global__ __launch_bounds__(1024) void k_iou(
    const u64* __restrict__ cand, const float4* __restrict__ boxes,
    const int* __restrict__ labels, u64* __restrict__ mask)
{
    __shared__ float sx1[1000], sy1[1000], sx2[1000], sy2[1000], sar[1000];
    int b = blockIdx.y, chunk = blockIdx.x, tid = threadIdx.x;
    const u64* cb = cand + (size_t)b * 1024;

    for (int i = tid; i < PRE_K; i += 1024) {
        u64 key = cb[i];
        u32 a = ~(u32)key;
        float4 bx = boxes[(size_t)b * NA + a];
        float off = (float)labels[(size_t)b * NA + a] * 8192.0f;  // exact mult
        float x1 = bx.x + off, y1 = bx.y + off, x2 = bx.z + off, y2 = bx.w + off;
        sx1[i] = x1; sy1[i] = y1; sx2[i] = x2; sy2[i] = y2;
        float w = fmaxf(__fsub_rn(x2, x1), 0.0f);
        float h = fmaxf(__fsub_rn(y2, y1), 0.0f);
        sar[i] = __fmul_rn(w, h);
    }
    __syncthreads();

    // 125 rows per chunk, 16 words per row = 2000 work items
    for (int w0 = tid; w0 < 2000; w0 += 1024) {
        int il = w0 % 125, jw = w0 / 125;
        int i = chunk * 125 + il;
        float ax1 = sx1[i], ay1 = sy1[i], ax2 = sx2[i], ay2 = sy2[i], aar = sar[i];
        int jmax = min(64, PRE_K - jw * 64);
        u64 bits = 0;
        for (int jj = 0; jj < jmax; ++jj) {
            int j = jw * 64 + jj;                 // uniform across wave -> LDS broadcast
            float lx = fmaxf(ax1, sx1[j]), ly = fmaxf(ay1, sy1[j]);
            float rx = fminf(ax2, sx2[j]), ry = fminf(ay2, sy2[j]);
            float ww = fmaxf(__fsub_rn(rx, lx), 0.0f);
            float hh = fmaxf(__fsub_rn(ry, ly), 0.0f);
            float inter = __fmul_rn(ww, hh);
            float uni = __fsub_rn(__fadd_rn(aar, sar[j]), inter);  // (ai+aj)-inter, no FMA
            float den = fmaxf(uni, 1e-6f);
            float iou = inter / den;
            if (iou > 0.65f) bits |= (1ull << jj);
        }
        mask[((size_t)b * PRE_K + i) * 16 + jw] = bits;
    }
}

// ------------------------------------------------------------------
// Kernel 4: serial greedy-NMS scan, mask staged in LDS in two phases
// (rows 0..511 = 64 KB, rows 512..999 = 61 KB), 1024-thread block:
// all 16 waves stream the half into LDS, wave 0 scans it (depth-4
// register pipeline over ds_read, ~120cyc LDS latency fully covered).
// R2 post-mortem: global-mask scan was cross-XCD latency-bound at
// 312 cyc/step; LDS brings the row fetch onto the CU.
// ------------------------------------------------------------------
__global__ __launch_bounds__(1024) void k_nms(
    const u64* __restrict__ cand, const float4* __restrict__ boxes,
    const int* __restrict__ labels, const u64* __restrict__ mask,
    float* __restrict__ out)
{
    __shared__ u64 sm[8192];                 // 64 KB, exactly rows 0..511
    int b = blockIdx.x, tid = threadIdx.x, lane = tid & 63;
    const u64* cb = cand + (size_t)b * 1024;
    const u64* mb = mask + (size_t)b * PRE_K * 16;
    int lw = lane & 15;   // row word this lane mirrors (replicated x4)

    // ---- phase 1 fill: rows 0..511 (words 0..8191) ----
    for (int w = tid; w < 8192; w += 1024) sm[w] = mb[w];

    // wave-0 scan state init while fill is in flight
    u64 sup = 0, cur = 0, keepm = 0;
    if (tid < 64) {
        for (int r = 0; r < 16; ++r) {
            int i = r * 64 + lane;
            u64 key = (i < PRE_K) ? cb[i] : 0ull;
            float sc = __uint_as_float((u32)(key >> 32));
            bool val = (i < PRE_K) && (sc > 0.25f);
            u64 mball = __ballot(val);
            if (lane == r) sup = ~mball;
        }
        cur = shfl64(sup, 0);
    }
    __syncthreads();

#define SCAN_PHASE(BASE, NSTEPS, REFRESH0)                                  \
    {                                                                        \
        u64 pr[4], ps[4];                                                    \
        _Pragma("unroll")                                                    \
        for (int d = 0; d < 4; ++d) {                                        \
            pr[d] = sm[d * 16 + lw];                                         \
            ps[d] = sm[d * 16 + (((BASE) + d) >> 6)];                        \
        }                                                                    \
        for (int t0 = 0; t0 < (NSTEPS); t0 += 4) {                           \
            int g0 = (BASE) + t0;                                            \
            if (((g0 & 63) == 0) && (t0 || (REFRESH0)))                      \
                cur = shfl64(sup, g0 >> 6);                                  \
            _Pragma("unroll")                                                \
            for (int u = 0; u < 4; ++u) {                                    \
                int t = t0 + u, g = g0 + u;                                  \
                u64 row = pr[u], sw = ps[u];                                 \
                int tp = t + 4; if (tp >= (NSTEPS)) tp = (NSTEPS) - 1;       \
                pr[u] = sm[tp * 16 + lw];                                    \
                ps[u] = sm[tp * 16 + (((BASE) + tp) >> 6)];                  \
                u64 bit = 1ull << (g & 63);                                  \
                u64 m = ((cur & bit) == 0) ? ~0ull : 0ull;                   \
                u64 lbit = (lane == (g >> 6)) ? bit : 0ull;                  \
                sup = (sup | (row & m)) & ~(lbit & m);                       \
                cur = (cur | (sw & m)) & ~(bit & m);                         \
                keepm |= lbit & m;                                           \
            }                                                                \
        }                                                                    \
    }

    if (tid < 64) SCAN_PHASE(0, 512, 0)
    __syncthreads();

    // ---- phase 2 fill: rows 512..999 (words 8192..15999) ----
    for (int w = tid; w < 7808; w += 1024) sm[w] = mb[8192 + w];
    __syncthreads();

    if (tid >= 64) return;                    // loaders done

    SCAN_PHASE(512, 488, 1)
#undef SCAN_PHASE

    // prefix of kept counts across the 16 chunks
    int cnt = __popcll(keepm);
    int pre = 0, K = 0;
    for (int w = 0; w < 16; ++w) {
        int c = __shfl(cnt, w, 64);
        if (w < lane) pre += c;
        K += c;
    }

    if (lane < 16) {
        for (int t = 0; t < 64; ++t) {
            int i = lane * 64 + t;
            if (i >= PRE_K) break;
            u64 bit = 1ull << t;
            int kb = __popcll(keepm & (bit - 1));
            int row; float fsc;
            u64 key = cb[i];
            if (keepm & bit) { row = pre + kb; fsc = __uint_as_float((u32)(key >> 32)); }
            else             { row = K + (i - (pre + kb)); fsc = 0.0f; }  // zero-score backfill, index order
            if (row < 100) {
                u32 a = ~(u32)key;
                float4 bx = boxes[(size_t)b * NA + a];
                int lab = labels[(size_t)b * NA + a];
                float* dr = out + (size_t)(b * 100 + row) * 5;
                dr[0] = bx.x; dr[1] = bx.y; dr[2] = bx.z; dr[3] = bx.w; dr[4] = fsc;
                out[(size_t)NB * 100 * 5 + b * 100 + row] = (float)lab;
            }
        }
    }
}

extern "C" void kernel_launch(void* const* d_in, const int* in_sizes, int n_in,
                              void* d_out, int out_size, void* d_ws, size_t ws_size,
                              hipStream_t stream) {
    const float* cls0 = (const float*)d_in[0];
    const float* cls1 = (const float*)d_in[1];
    const float* cls2 = (const float*)d_in[2];
    const float* box0 = (const float*)d_in[3];
    const float* box1 = (const float*)d_in[4];
    const float* box2 = (const float*)d_in[5];
    float* out = (float*)d_out;

    char* w = (char*)d_ws;
    u64*    f_keys = (u64*)(w);
    float4* boxes  = (float4*)(w + 1075200);
    int*    labels = (int*)(w + 3225600);
    u64*    cand   = (u64*)(w + 3763200);
    u64*    mask   = (u64*)(w + 3894272);

    k_decode<<<dim3(33, NB), 256, 0, stream>>>(cls0, cls1, cls2, box0, box1, box2,
                                               f_keys, boxes, labels);
    k_sort<<<NB, 1024, 0, stream>>>(f_keys, cand);
    k_iou<<<dim3(8, NB), 1024, 0, stream>>>(cand, boxes, labels, mask);
    k_nms<<<NB, 1024, 0, stream>>>(cand, boxes, labels, mask, out);
}